// Round 6
// baseline (155.218 us; speedup 1.0000x reference)
//
#include <hip/hip_runtime.h>
#include <math.h>

// IIR biquad cascade (K=4), B=64, C=2, L=131072 -> 128 independent rows.
// R11 = R10 resubmit (R9: container failed twice; R10: GPU acquisition
// timeout — neither ever ran; code untested, theory unchanged).
// Two-kernel superposition with y0 parked in the OUTPUT buffer.
//  K1: zero-state chunk run; y0 written to out (cached stores, proven LDS
//      transpose path); end-state d -> workspace.
//  K2: p = sum N_{m-1} d_{j-m} (verified R6 math), then streaming correction
//      y[t] = y0[t] + (C A^t).p  (verified R7 algebra; 8 FMA/sample, NO serial
//      recurrence, y0 re-read is L3-resident). Replaces R6/R8's full 20-FMA
//      recompute pass. Cooperative path dropped (R8: net neutral vs R6).
// Fallback: R5 warm-up kernel if workspace/shape unsuitable.

#define SS   64    // output samples per lane (chunk size)
#define WMAX 384   // max warm-up horizon (calibrated at r=0.95)
#define WMIN 64
#define TT   32    // time-tile staged per LDS round
#define TPB  256   // threads per block (= chunks per block)
#define LSTR 33    // LDS row stride in floats (odd => 2-way = conflict-free)
#define KB   4     // biquads in cascade
#define NL   8     // float4 loads per thread per tile
#define HALO 6     // max chunk lookback (= WMAX/SS)
#define DSTR 9     // padded d stride in LDS (9 coprime 32 => conflict-free)

typedef float vf4 __attribute__((ext_vector_type(4)));

// ============ prep: A-powers (N_1..N_5), w_t = C A^t, nW  (R7-verified) ====
__global__ void iir_prep3_kernel(const float* __restrict__ Bs,
                                 const float* __restrict__ As, int rows,
                                 int* __restrict__ nwrow,
                                 float* __restrict__ nmat,
                                 float* __restrict__ wmat)
{
    __shared__ float mat[4][5][64];   // 0,1: ping-pong; 2: N1; 3: A copy; 4: C
    const int grp  = threadIdx.x >> 6;
    const int lane = threadIdx.x & 63;
    const int row  = blockIdx.x * 4 + grp;
    const bool act = (row < rows);

    float b0[KB], b1[KB], b2[KB], na1[KB], na2[KB];
    if (act) {
        const float* Bp = Bs + (size_t)row * KB * 3;
        const float* Ap = As + (size_t)row * KB * 3;
#pragma unroll
        for (int k = 0; k < KB; ++k) {
            float inv = 1.0f / Ap[3 * k];
            b0[k]  =  Bp[3 * k]     * inv;
            b1[k]  =  Bp[3 * k + 1] * inv;
            b2[k]  =  Bp[3 * k + 2] * inv;
            na1[k] = -Ap[3 * k + 1] * inv;
            na2[k] = -Ap[3 * k + 2] * inv;
        }
    }

    float* cur = &mat[grp][0][0];
    float* nxt = &mat[grp][1][0];
    float* n1  = &mat[grp][2][0];
    float* ac  = &mat[grp][3][0];
    float* cw  = &mat[grp][4][0];

    // Build A column-by-column: column j = one filter step from s=e_j, x=0.
    // The cascade's final u for that start state IS the output row C_j.
    if (act && lane < 8) {
        float s[8];
#pragma unroll
        for (int i = 0; i < 8; ++i) s[i] = (i == lane) ? 1.0f : 0.0f;
        float u = 0.0f;
#pragma unroll
        for (int k = 0; k < KB; ++k) {
            float y  = fmaf(b0[k], u, s[2 * k]);
            float t1 = fmaf(na1[k], y, fmaf(b1[k], u, s[2 * k + 1]));
            float t2 = fmaf(na2[k], y, b2[k] * u);
            s[2 * k] = t1; s[2 * k + 1] = t2; u = y;
        }
#pragma unroll
        for (int i = 0; i < 8; ++i) { cur[i * 8 + lane] = s[i]; ac[i * 8 + lane] = s[i]; }
        cw[lane] = u;                              // C_j
    }
    __syncthreads();

    const int i8 = lane >> 3, j8 = lane & 7;

    // A^64 via 6 squarings
    for (int t = 0; t < 6; ++t) {
        float acc = 0.0f;
        if (act) {
#pragma unroll
            for (int m = 0; m < 8; ++m)
                acc = fmaf(cur[i8 * 8 + m], cur[m * 8 + j8], acc);
            nxt[lane] = acc;
        }
        __syncthreads();
        float* t0 = cur; cur = nxt; nxt = t0;
    }

    if (act) {
        float v = cur[lane];                       // N1 = A^64
        n1[lane] = v;
        nmat[(size_t)row * 320 + lane] = v;
    }
    __syncthreads();

    // N_m = N_{m-1} * N1, m = 2..5
    for (int m = 2; m <= 5; ++m) {
        float acc = 0.0f;
        if (act) {
#pragma unroll
            for (int q = 0; q < 8; ++q)
                acc = fmaf(cur[i8 * 8 + q], n1[q * 8 + j8], acc);
            nxt[lane] = acc;
            nmat[(size_t)row * 320 + (m - 1) * 64 + lane] = acc;
        }
        __syncthreads();
        float* t0 = cur; cur = nxt; nxt = t0;
    }
    __syncthreads();

    // w_t = C A^t, t=0..63: lane j (<8) owns component j; shfl-broadcast dot.
    if (act && lane < 8) {
        float Ac[8];
#pragma unroll
        for (int i = 0; i < 8; ++i) Ac[i] = ac[i * 8 + lane];  // column `lane` of A
        float w = cw[lane];                                    // C_lane
        float* wm = wmat + (size_t)row * 512;
        for (int t = 0; t < SS; ++t) {
            wm[t * 8 + lane] = w;
            float acc = 0.0f;
#pragma unroll
            for (int i = 0; i < 8; ++i)
                acc = fmaf(__shfl(w, i, 8), Ac[i], acc);       // (w^T A)_lane
            w = acc;
        }
    }

    // per-row lookback count nW = ceil(W/64), same W formula as R4..R8
    if (act && lane == 0) {
        const float* Ap = As + (size_t)row * KB * 3;
        float r2max = 0.0f;
#pragma unroll
        for (int k = 0; k < KB; ++k) {
            float a0 = Ap[3 * k];
            float a2 = Ap[3 * k + 2] / a0;         // = r^2
            r2max = fmaxf(r2max, a2);
        }
        float rmax = fminf(fmaxf(sqrtf(fmaxf(r2max, 0.f)), 0.20f), 0.955f);
        float Wf = 25.6f / (-logf(rmax));
        int W = ((int)ceilf(Wf) + TT - 1) & ~(TT - 1);
        W = min(max(W, WMIN), WMAX);
        nwrow[row] = (W + SS - 1) / SS;            // 1..6
    }
}

// ============ K1: zero-state run; y0 -> out (cached), d -> workspace =======
__global__ __launch_bounds__(TPB, 4) void iir_state_y0_kernel(
    const float* __restrict__ x, const float* __restrict__ Bs,
    const float* __restrict__ As, float* __restrict__ out, int L,
    float* __restrict__ dstate)
{
    __shared__ float lds[TPB * LSTR];
    const int tid = threadIdx.x;
    const int cpr = L / SS;
    const int bpr = cpr / TPB;
    const int row = blockIdx.x / bpr;
    const int chunk0 = (blockIdx.x % bpr) * TPB;

    float b0[KB], b1[KB], b2[KB], na1[KB], na2[KB];
    const float* Bp = Bs + (size_t)row * KB * 3;
    const float* Ap = As + (size_t)row * KB * 3;
#pragma unroll
    for (int k = 0; k < KB; ++k) {
        float inv = 1.0f / Ap[3 * k];
        b0[k]  =  Bp[3 * k]     * inv;
        b1[k]  =  Bp[3 * k + 1] * inv;
        b2[k]  =  Bp[3 * k + 2] * inv;
        na1[k] = -Ap[3 * k + 1] * inv;
        na2[k] = -Ap[3 * k + 2] * inv;
    }

    float s1[KB] = {0.f, 0.f, 0.f, 0.f};
    float s2[KB] = {0.f, 0.f, 0.f, 0.f};

    const float* xrow = x   + (size_t)row * L;
    float*       orow = out + (size_t)row * L;
    float*       myrow = lds + tid * LSTR;

    const int tq = tid >> 3;
    const int p4 = (tid & 7) << 2;
    int off[NL], ldsoff[NL];
#pragma unroll
    for (int l = 0; l < NL; ++l) {
        int j = l * 32 + tq;
        off[l]    = (chunk0 + j) * SS + p4;   // always in [0, L)
        ldsoff[l] = j * LSTR + p4;
    }

    float4 rn[NL];
#pragma unroll
    for (int l = 0; l < NL; ++l)
        rn[l] = *reinterpret_cast<const float4*>(xrow + off[l]);

#pragma unroll
    for (int it = 0; it < SS / TT; ++it) {
        __syncthreads();
#pragma unroll
        for (int l = 0; l < NL; ++l) {
            float* d = lds + ldsoff[l];
            d[0] = rn[l].x; d[1] = rn[l].y; d[2] = rn[l].z; d[3] = rn[l].w;
        }
        if (it + 1 < SS / TT) {
            const int base = (it + 1) * TT;
#pragma unroll
            for (int l = 0; l < NL; ++l)
                rn[l] = *reinterpret_cast<const float4*>(xrow + off[l] + base);
        }
        __syncthreads();

#pragma unroll
        for (int p = 0; p < TT; ++p) {
            float u = myrow[p];
#pragma unroll
            for (int k = 0; k < KB; ++k) {
                float yv = fmaf(b0[k], u, s1[k]);
                s1[k] = fmaf(na1[k], yv, fmaf(b1[k], u, s2[k]));
                s2[k] = fmaf(na2[k], yv, b2[k] * u);
                u = yv;
            }
            myrow[p] = u;            // y0 back into LDS
        }
        __syncthreads();

        // y0 -> out with PLAIN (cached) stores: K2 re-reads this from L3
        const int base = it * TT;
#pragma unroll
        for (int l = 0; l < NL; ++l) {
            const float* sp = lds + ldsoff[l];
            float4 v = make_float4(sp[0], sp[1], sp[2], sp[3]);
            *reinterpret_cast<float4*>(orow + off[l] + base) = v;
        }
    }

    // end state of this chunk, coalesced 32B per lane
    float* dp = dstate + ((size_t)row * cpr + chunk0 + tid) * 8;
    *reinterpret_cast<float4*>(dp)     = make_float4(s1[0], s2[0], s1[1], s2[1]);
    *reinterpret_cast<float4*>(dp + 4) = make_float4(s1[2], s2[2], s1[3], s2[3]);
}

// ============ K2: streaming correction y = y0 + (C A^t).p ==================
__global__ __launch_bounds__(TPB, 4) void iir_corr_kernel(
    float* __restrict__ out, int L,
    const float* __restrict__ dstate, const float* __restrict__ nmat,
    const float* __restrict__ wmat, const int* __restrict__ nwrow)
{
    __shared__ float lds[TPB * LSTR + 512];   // staging + resident W-rows
    float* wl = lds + TPB * LSTR;             // 512 floats, never overwritten
    const int tid = threadIdx.x;
    const int cpr = L / SS;
    const int bpr = cpr / TPB;
    const int row = blockIdx.x / bpr;
    const int chunk0 = (blockIdx.x % bpr) * TPB;
    const int nW = nwrow[row];

    float* orow  = out + (size_t)row * L;
    float* myrow = lds + tid * LSTR;

    const int tq = tid >> 3;
    const int p4 = (tid & 7) << 2;
    int off[NL], ldsoff[NL];
#pragma unroll
    for (int l = 0; l < NL; ++l) {
        int j = l * 32 + tq;
        off[l]    = (chunk0 + j) * SS + p4;
        ldsoff[l] = j * LSTR + p4;
    }

    // tile-0 y0 prefetch: in flight under the d/N/W staging + matvec
    float4 rn[NL];
#pragma unroll
    for (int l = 0; l < NL; ++l)
        rn[l] = *reinterpret_cast<const float4*>(orow + off[l]);

    // ---- stage d window + N matrices + W rows (base pointer in-bounds) ----
    float* dl = lds;                          // (TPB+HALO)*DSTR = 2358 floats
    float* nl = lds + (TPB + HALO) * DSTR;    // 320 floats
    const float* drow = dstate + (size_t)row * cpr * 8;
    for (int e = tid; e < (TPB + HALO) * 8; e += TPB) {
        int c  = e >> 3;
        int gi = chunk0 - HALO + c;           // signed chunk index
        float v = 0.0f;
        if (gi >= 0) v = drow[(size_t)gi * 8 + (e & 7)];   // guarded: no OOB
        dl[c * DSTR + (e & 7)] = v;
    }
    for (int e = tid; e < 320; e += TPB) nl[e] = nmat[(size_t)row * 320 + e];
    for (int e = tid; e < 512; e += TPB) wl[e] = wmat[(size_t)row * 512 + e];
    __syncthreads();

    // ---- exact chunk-start state: p = sum_{m=1..nW} N_{m-1} d_{j-m} ----
    float pst[8];
#pragma unroll
    for (int i = 0; i < 8; ++i) pst[i] = dl[(tid + HALO - 1) * DSTR + i];
#pragma unroll 1
    for (int m = 2; m <= nW; ++m) {
        const float* M  = nl + (m - 2) * 64;            // broadcast reads
        const float* dd = dl + (tid + HALO - m) * DSTR; // stride-9: conflict-free
        float din[8];
#pragma unroll
        for (int q = 0; q < 8; ++q) din[q] = dd[q];
#pragma unroll
        for (int i = 0; i < 8; ++i) {
            float a = pst[i];
#pragma unroll
            for (int q = 0; q < 8; ++q) a = fmaf(M[i * 8 + q], din[q], a);
            pst[i] = a;
        }
    }

    // ---- streaming correction: no recurrence, 8 FMA/sample ----
#pragma unroll
    for (int it = 0; it < SS / TT; ++it) {
        __syncthreads();   // fences dl/nl reads (it=0) / prior tile reads
#pragma unroll
        for (int l = 0; l < NL; ++l) {
            float* d = lds + ldsoff[l];
            d[0] = rn[l].x; d[1] = rn[l].y; d[2] = rn[l].z; d[3] = rn[l].w;
        }
        if (it + 1 < SS / TT) {
            const int base = (it + 1) * TT;
#pragma unroll
            for (int l = 0; l < NL; ++l)
                rn[l] = *reinterpret_cast<const float4*>(orow + off[l] + base);
        }
        __syncthreads();

#pragma unroll
        for (int q = 0; q < TT; ++q) {
            const int t = it * TT + q;
            float a = myrow[q];
#pragma unroll
            for (int i = 0; i < 8; ++i)
                a = fmaf(wl[t * 8 + i], pst[i], a);   // wl: broadcast reads
            myrow[q] = a;
        }
        __syncthreads();

        const int base = it * TT;
#pragma unroll
        for (int l = 0; l < NL; ++l) {
            const float* sp = lds + ldsoff[l];
            vf4 v = { sp[0], sp[1], sp[2], sp[3] };
            __builtin_nontemporal_store(
                v, reinterpret_cast<vf4*>(orow + off[l] + base));
        }
    }
}

// ===================== fallback path (R5, proven) ==========================
__global__ void iir_prep_kernel(const float* __restrict__ As, int rows,
                                int* __restrict__ wrow, int* __restrict__ perm)
{
    __shared__ int sw[256];
    const int r = threadIdx.x;
    int W = 0;
    if (r < rows) {
        float r2max = 0.f;
#pragma unroll
        for (int k = 0; k < KB; ++k) {
            float a0 = As[(size_t)r * KB * 3 + 3 * k];
            float a2 = As[(size_t)r * KB * 3 + 3 * k + 2] / a0;
            r2max = fmaxf(r2max, a2);
        }
        float rmax = fminf(fmaxf(sqrtf(fmaxf(r2max, 0.f)), 0.20f), 0.955f);
        float Wf = 25.6f / (-logf(rmax));
        W = ((int)ceilf(Wf) + TT - 1) & ~(TT - 1);
        W = min(max(W, WMIN), WMAX);
        wrow[r] = W;
    }
    sw[r] = W;
    __syncthreads();
    if (r < rows) {
        int rank = 0;
        for (int i = 0; i < rows; ++i)
            rank += (sw[i] > W) || (sw[i] == W && i < r);
        perm[rank] = r;
    }
}

__global__ __launch_bounds__(TPB, 4) void iir_chunks_kernel(
    const float* __restrict__ x, const float* __restrict__ Bs,
    const float* __restrict__ As, float* __restrict__ out, int L,
    const int* __restrict__ wrow, const int* __restrict__ perm)
{
    __shared__ float lds[TPB * LSTR];
    const int tid = threadIdx.x;
    const int bpr = (L / SS) / TPB;
    const int row = perm[blockIdx.x / bpr];
    const int chunk0 = (blockIdx.x % bpr) * TPB;
    const int W = wrow[row];

    float b0[KB], b1[KB], b2[KB], na1[KB], na2[KB];
    const float* Bp = Bs + (size_t)row * KB * 3;
    const float* Ap = As + (size_t)row * KB * 3;
#pragma unroll
    for (int k = 0; k < KB; ++k) {
        float inv = 1.0f / Ap[3 * k];
        b0[k]  =  Bp[3 * k]     * inv;
        b1[k]  =  Bp[3 * k + 1] * inv;
        b2[k]  =  Bp[3 * k + 2] * inv;
        na1[k] = -Ap[3 * k + 1] * inv;
        na2[k] = -Ap[3 * k + 2] * inv;
    }

    float s1[KB] = {0.f, 0.f, 0.f, 0.f};
    float s2[KB] = {0.f, 0.f, 0.f, 0.f};

    const float* xrow = x   + (size_t)row * L;
    float*       orow = out + (size_t)row * L;
    float*       myrow = lds + tid * LSTR;

    const int tq = tid >> 3;
    const int p4 = (tid & 7) << 2;
    int off[NL], ldsoff[NL];
#pragma unroll
    for (int l = 0; l < NL; ++l) {
        int j = l * 32 + tq;
        off[l]    = (chunk0 + j) * SS + p4 - W;
        ldsoff[l] = j * LSTR + p4;
    }

    const int NT = (SS + W) / TT;
    const int WT = W / TT;

    float4 rn[NL];
#pragma unroll
    for (int l = 0; l < NL; ++l) {
        int pos = off[l];
        rn[l] = make_float4(0.f, 0.f, 0.f, 0.f);
        if (pos >= 0) rn[l] = *reinterpret_cast<const float4*>(xrow + pos);
    }

#pragma unroll 1
    for (int it = 0; it < NT; ++it) {
        __syncthreads();
#pragma unroll
        for (int l = 0; l < NL; ++l) {
            float* d = lds + ldsoff[l];
            d[0] = rn[l].x; d[1] = rn[l].y; d[2] = rn[l].z; d[3] = rn[l].w;
        }
        if (it + 1 < NT) {
            const int base = (it + 1) * TT;
#pragma unroll
            for (int l = 0; l < NL; ++l) {
                int pos = off[l] + base;
                rn[l] = make_float4(0.f, 0.f, 0.f, 0.f);
                if (pos >= 0) rn[l] = *reinterpret_cast<const float4*>(xrow + pos);
            }
        }
        __syncthreads();

        if (it < WT) {
#pragma unroll
            for (int p = 0; p < TT; ++p) {
                float u = myrow[p];
#pragma unroll
                for (int k = 0; k < KB; ++k) {
                    float yv = fmaf(b0[k], u, s1[k]);
                    s1[k] = fmaf(na1[k], yv, fmaf(b1[k], u, s2[k]));
                    s2[k] = fmaf(na2[k], yv, b2[k] * u);
                    u = yv;
                }
            }
        } else {
#pragma unroll
            for (int p = 0; p < TT; ++p) {
                float u = myrow[p];
#pragma unroll
                for (int k = 0; k < KB; ++k) {
                    float yv = fmaf(b0[k], u, s1[k]);
                    s1[k] = fmaf(na1[k], yv, fmaf(b1[k], u, s2[k]));
                    s2[k] = fmaf(na2[k], yv, b2[k] * u);
                    u = yv;
                }
                myrow[p] = u;
            }
            __syncthreads();

            const int base = it * TT - W;
#pragma unroll
            for (int l = 0; l < NL; ++l) {
                const float* sp = lds + ldsoff[l];
                vf4 v = { sp[0], sp[1], sp[2], sp[3] };
                __builtin_nontemporal_store(
                    v, reinterpret_cast<vf4*>(orow + off[l] + W + base));
            }
        }
    }
}

// ============================== launch =====================================
extern "C" void kernel_launch(void* const* d_in, const int* in_sizes, int n_in,
                              void* d_out, int out_size, void* d_ws, size_t ws_size,
                              hipStream_t stream) {
    const float* x  = (const float*)d_in[0];   // (B, C, L) f32
    const float* Bs = (const float*)d_in[1];   // (B, C, K, 3) f32
    const float* As = (const float*)d_in[2];   // (B, C, K, 3) f32
    float* out = (float*)d_out;                // (B, C, L) f32

    const int rows = in_sizes[1] / (KB * 3);   // B*C = 128
    const int L    = in_sizes[0] / rows;       // 131072
    const int cpr  = L / SS;                   // 2048 chunks per row
    const int bpr  = cpr / TPB;                // 8 blocks per row
    const int grid = rows * bpr;               // 1024

    // workspace layout
    float* dstate = (float*)d_ws;                              // rows*cpr*8
    float* nmatp  = dstate + (size_t)rows * cpr * 8;           // rows*320
    float* wmatp  = nmatp  + (size_t)rows * 320;               // rows*512
    int*   nwrowp = (int*)(wmatp + (size_t)rows * 512);        // rows
    const size_t need = (size_t)((char*)(nwrowp + rows) - (char*)d_ws);

    if ((L % SS) == 0 && bpr * TPB == cpr && ws_size >= need) {
        hipLaunchKernelGGL(iir_prep3_kernel, dim3((rows + 3) / 4), dim3(256), 0,
                           stream, Bs, As, rows, nwrowp, nmatp, wmatp);
        hipLaunchKernelGGL(iir_state_y0_kernel, dim3(grid), dim3(TPB), 0,
                           stream, x, Bs, As, out, L, dstate);
        hipLaunchKernelGGL(iir_corr_kernel, dim3(grid), dim3(TPB), 0,
                           stream, out, L, dstate, nmatp, wmatp, nwrowp);
    } else {
        int* wrow = (int*)d_ws;
        int* perm = wrow + rows;
        hipLaunchKernelGGL(iir_prep_kernel, dim3(1), dim3(256), 0, stream,
                           As, rows, wrow, perm);
        hipLaunchKernelGGL(iir_chunks_kernel, dim3(rows * bpr), dim3(TPB), 0,
                           stream, x, Bs, As, out, L, wrow, perm);
    }
}

// Round 7
// 130.024 us; speedup vs baseline: 1.1938x; 1.1938x over previous
//
#include <hip/hip_runtime.h>
#include <math.h>

// IIR biquad cascade (K=4), B=64, C=2, L=131072 -> 128 independent rows.
// R12: revert to the VERIFIED R6 two-pass recompute structure (133.3us best
// measured) and fold the prep kernel into K1.
//  Lesson from R11 (155us): K2 is memory/latency-bound, so its 20-FMA/sample
//  recompute is effectively FREE; parking y0 in `out` added a 128MB round
//  trip and lost 22us. Keep the recompute, kill the extra traffic.
//  K1: zero-state chunk run -> d states (R6 body verbatim). The first block
//      of each row (blockIdx.x % bpr == 0; block-uniform branch) additionally
//      computes that row's N-matrices (A^64 powers) + nW inline and writes
//      them to workspace -- K2 is the only consumer and stream order
//      guarantees visibility. Removes one dispatch + launch gap.
//  K2: p = sum N_{m-1} d_{j-m}, then recompute chunk from exact state
//      (R6 body verbatim, in-bounds d-staging).
// Fallback: R5 warm-up kernel if workspace/shape unsuitable.

#define SS   64    // output samples per lane (chunk size)
#define WMAX 384   // max warm-up horizon (calibrated at r=0.95)
#define WMIN 64
#define TT   32    // time-tile staged per LDS round
#define TPB  256   // threads per block (= chunks per block)
#define LSTR 33    // LDS row stride in floats (odd => 2-way = conflict-free)
#define KB   4     // biquads in cascade
#define NL   8     // float4 loads per thread per tile
#define HALO 6     // max chunk lookback (= WMAX/SS)
#define DSTR 9     // padded d stride in LDS (9 coprime 32 => conflict-free)

typedef float vf4 __attribute__((ext_vector_type(4)));

// ============ K1: zero-state run -> d; row-leader blocks also do prep ======
__global__ __launch_bounds__(TPB, 4) void iir_state_kernel(
    const float* __restrict__ x, const float* __restrict__ Bs,
    const float* __restrict__ As, int L, float* __restrict__ dstate,
    float* __restrict__ nmat, int* __restrict__ nwrow)
{
    __shared__ float lds[TPB * LSTR];
    const int tid = threadIdx.x;
    const int cpr = L / SS;
    const int bpr = cpr / TPB;
    const int row = blockIdx.x / bpr;
    const int chunk0 = (blockIdx.x % bpr) * TPB;

    float b0[KB], b1[KB], b2[KB], na1[KB], na2[KB];
    const float* Bp = Bs + (size_t)row * KB * 3;
    const float* Ap = As + (size_t)row * KB * 3;
#pragma unroll
    for (int k = 0; k < KB; ++k) {
        float inv = 1.0f / Ap[3 * k];
        b0[k]  =  Bp[3 * k]     * inv;
        b1[k]  =  Bp[3 * k + 1] * inv;
        b2[k]  =  Bp[3 * k + 2] * inv;
        na1[k] = -Ap[3 * k + 1] * inv;
        na2[k] = -Ap[3 * k + 2] * inv;
    }

    float s1[KB] = {0.f, 0.f, 0.f, 0.f};
    float s2[KB] = {0.f, 0.f, 0.f, 0.f};

    const float* xrow = x + (size_t)row * L;
    float* myrow = lds + tid * LSTR;

    const int tq = tid >> 3;
    const int p4 = (tid & 7) << 2;
    int off[NL], ldsoff[NL];
#pragma unroll
    for (int l = 0; l < NL; ++l) {
        int j = l * 32 + tq;
        off[l]    = (chunk0 + j) * SS + p4;   // always in [0, L)
        ldsoff[l] = j * LSTR + p4;
    }

    // issue tile-0 prefetch first: in flight under the (leader-only) prep
    float4 rn[NL];
#pragma unroll
    for (int l = 0; l < NL; ++l)
        rn[l] = *reinterpret_cast<const float4*>(xrow + off[l]);

    // ---- inline prep: one block per row computes nmat + nwrow ----
    // Block-uniform branch => __syncthreads inside is legal. LDS scratch
    // [0,192) is dead before the main loop's first barrier + staging.
    if ((blockIdx.x % bpr) == 0) {
        float* cur = lds;          // 64 floats
        float* nxt = lds + 64;     // 64 floats
        float* n1  = lds + 128;    // 64 floats

        // Build A column-by-column: column j = one step from s=e_j, x=0.
        if (tid < 8) {
            float s[8];
#pragma unroll
            for (int i = 0; i < 8; ++i) s[i] = (i == tid) ? 1.0f : 0.0f;
            float u = 0.0f;
#pragma unroll
            for (int k = 0; k < KB; ++k) {
                float y  = fmaf(b0[k], u, s[2 * k]);
                float t1 = fmaf(na1[k], y, fmaf(b1[k], u, s[2 * k + 1]));
                float t2 = fmaf(na2[k], y, b2[k] * u);
                s[2 * k] = t1; s[2 * k + 1] = t2; u = y;
            }
#pragma unroll
            for (int i = 0; i < 8; ++i) cur[i * 8 + tid] = s[i];   // A[i][j]
        }
        __syncthreads();

        const int i8 = tid >> 3, j8 = tid & 7;

        // A^64 via 6 squarings
        for (int t = 0; t < 6; ++t) {
            if (tid < 64) {
                float acc = 0.0f;
#pragma unroll
                for (int m = 0; m < 8; ++m)
                    acc = fmaf(cur[i8 * 8 + m], cur[m * 8 + j8], acc);
                nxt[tid] = acc;
            }
            __syncthreads();
            float* t0 = cur; cur = nxt; nxt = t0;
        }

        if (tid < 64) {
            float v = cur[tid];                    // N1 = A^64
            n1[tid] = v;
            nmat[(size_t)row * 320 + tid] = v;
        }
        __syncthreads();

        // N_m = N_{m-1} * N1, m = 2..5
        for (int m = 2; m <= 5; ++m) {
            if (tid < 64) {
                float acc = 0.0f;
#pragma unroll
                for (int q = 0; q < 8; ++q)
                    acc = fmaf(cur[i8 * 8 + q], n1[q * 8 + j8], acc);
                nxt[tid] = acc;
                nmat[(size_t)row * 320 + (m - 1) * 64 + tid] = acc;
            }
            __syncthreads();
            float* t0 = cur; cur = nxt; nxt = t0;
        }

        // per-row lookback count nW = ceil(W/64), same W formula as R4..R11
        if (tid == 0) {
            float r2max = 0.0f;
#pragma unroll
            for (int k = 0; k < KB; ++k) {
                float a0 = Ap[3 * k];
                float a2 = Ap[3 * k + 2] / a0;     // = r^2
                r2max = fmaxf(r2max, a2);
            }
            float rmax = fminf(fmaxf(sqrtf(fmaxf(r2max, 0.f)), 0.20f), 0.955f);
            float Wf = 25.6f / (-logf(rmax));
            int W = ((int)ceilf(Wf) + TT - 1) & ~(TT - 1);
            W = min(max(W, WMIN), WMAX);
            nwrow[row] = (W + SS - 1) / SS;        // 1..6
        }
        // no trailing barrier needed: main loop opens with __syncthreads()
    }

    // ---- main zero-state loop (R6 body verbatim) ----
#pragma unroll
    for (int it = 0; it < SS / TT; ++it) {
        __syncthreads();
#pragma unroll
        for (int l = 0; l < NL; ++l) {
            float* d = lds + ldsoff[l];
            d[0] = rn[l].x; d[1] = rn[l].y; d[2] = rn[l].z; d[3] = rn[l].w;
        }
        if (it + 1 < SS / TT) {
            const int base = (it + 1) * TT;
#pragma unroll
            for (int l = 0; l < NL; ++l)
                rn[l] = *reinterpret_cast<const float4*>(xrow + off[l] + base);
        }
        __syncthreads();

#pragma unroll
        for (int p = 0; p < TT; ++p) {
            float u = myrow[p];
#pragma unroll
            for (int k = 0; k < KB; ++k) {
                float yv = fmaf(b0[k], u, s1[k]);
                s1[k] = fmaf(na1[k], yv, fmaf(b1[k], u, s2[k]));
                s2[k] = fmaf(na2[k], yv, b2[k] * u);
                u = yv;
            }
        }
    }

    // end state of this chunk, coalesced 32B per lane
    float* dp = dstate + ((size_t)row * cpr + chunk0 + tid) * 8;
    *reinterpret_cast<float4*>(dp)     = make_float4(s1[0], s2[0], s1[1], s2[1]);
    *reinterpret_cast<float4*>(dp + 4) = make_float4(s1[2], s2[2], s1[3], s2[3]);
}

// ============ K2: exact-state recompute (R6 body, verified @133us) =========
__global__ __launch_bounds__(TPB, 4) void iir_out_kernel(
    const float* __restrict__ x, const float* __restrict__ Bs,
    const float* __restrict__ As, float* __restrict__ out, int L,
    const float* __restrict__ dstate, const float* __restrict__ nmat,
    const int* __restrict__ nwrow)
{
    __shared__ float lds[TPB * LSTR];
    const int tid = threadIdx.x;
    const int cpr = L / SS;
    const int bpr = cpr / TPB;
    const int row = blockIdx.x / bpr;
    const int chunk0 = (blockIdx.x % bpr) * TPB;
    const int nW = nwrow[row];

    float b0[KB], b1[KB], b2[KB], na1[KB], na2[KB];
    const float* Bp = Bs + (size_t)row * KB * 3;
    const float* Ap = As + (size_t)row * KB * 3;
#pragma unroll
    for (int k = 0; k < KB; ++k) {
        float inv = 1.0f / Ap[3 * k];
        b0[k]  =  Bp[3 * k]     * inv;
        b1[k]  =  Bp[3 * k + 1] * inv;
        b2[k]  =  Bp[3 * k + 2] * inv;
        na1[k] = -Ap[3 * k + 1] * inv;
        na2[k] = -Ap[3 * k + 2] * inv;
    }

    const float* xrow = x   + (size_t)row * L;
    float*       orow = out + (size_t)row * L;
    float*       myrow = lds + tid * LSTR;

    const int tq = tid >> 3;
    const int p4 = (tid & 7) << 2;
    int off[NL], ldsoff[NL];
#pragma unroll
    for (int l = 0; l < NL; ++l) {
        int j = l * 32 + tq;
        off[l]    = (chunk0 + j) * SS + p4;
        ldsoff[l] = j * LSTR + p4;
    }

    // tile-0 x prefetch: in flight under the d/N staging + matvec
    float4 rn[NL];
#pragma unroll
    for (int l = 0; l < NL; ++l)
        rn[l] = *reinterpret_cast<const float4*>(xrow + off[l]);

    // ---- stage d window + N matrices (base pointer in-bounds) ----
    float* dl = lds;                          // (TPB+HALO)*DSTR = 2358 floats
    float* nl = lds + (TPB + HALO) * DSTR;    // 320 floats
    const float* drow = dstate + (size_t)row * cpr * 8;
    for (int e = tid; e < (TPB + HALO) * 8; e += TPB) {
        int c  = e >> 3;
        int gi = chunk0 - HALO + c;           // signed chunk index
        float v = 0.0f;
        if (gi >= 0) v = drow[(size_t)gi * 8 + (e & 7)];   // guarded: no OOB
        dl[c * DSTR + (e & 7)] = v;
    }
    for (int e = tid; e < 320; e += TPB) nl[e] = nmat[(size_t)row * 320 + e];
    __syncthreads();

    // ---- exact chunk-start state: p = sum_{m=1..nW} N_{m-1} d_{j-m} ----
    float pst[8];
#pragma unroll
    for (int i = 0; i < 8; ++i) pst[i] = dl[(tid + HALO - 1) * DSTR + i];
#pragma unroll 1
    for (int m = 2; m <= nW; ++m) {
        const float* M  = nl + (m - 2) * 64;            // broadcast reads
        const float* dd = dl + (tid + HALO - m) * DSTR; // stride-9: conflict-free
        float din[8];
#pragma unroll
        for (int q = 0; q < 8; ++q) din[q] = dd[q];
#pragma unroll
        for (int i = 0; i < 8; ++i) {
            float a = pst[i];
#pragma unroll
            for (int q = 0; q < 8; ++q) a = fmaf(M[i * 8 + q], din[q], a);
            pst[i] = a;
        }
    }
    float s1[KB], s2[KB];
#pragma unroll
    for (int k = 0; k < KB; ++k) { s1[k] = pst[2 * k]; s2[k] = pst[2 * k + 1]; }

    // ---- recompute chunk from exact state; y via LDS transpose, NT store --
#pragma unroll
    for (int it = 0; it < SS / TT; ++it) {
        __syncthreads();   // fences dl/nl reads before staging overwrite
#pragma unroll
        for (int l = 0; l < NL; ++l) {
            float* d = lds + ldsoff[l];
            d[0] = rn[l].x; d[1] = rn[l].y; d[2] = rn[l].z; d[3] = rn[l].w;
        }
        if (it + 1 < SS / TT) {
            const int base = (it + 1) * TT;
#pragma unroll
            for (int l = 0; l < NL; ++l)
                rn[l] = *reinterpret_cast<const float4*>(xrow + off[l] + base);
        }
        __syncthreads();

#pragma unroll
        for (int q = 0; q < TT; ++q) {
            float u = myrow[q];
#pragma unroll
            for (int k = 0; k < KB; ++k) {
                float yv = fmaf(b0[k], u, s1[k]);
                s1[k] = fmaf(na1[k], yv, fmaf(b1[k], u, s2[k]));
                s2[k] = fmaf(na2[k], yv, b2[k] * u);
                u = yv;
            }
            myrow[q] = u;
        }
        __syncthreads();

        const int base = it * TT;
#pragma unroll
        for (int l = 0; l < NL; ++l) {
            const float* sp = lds + ldsoff[l];
            vf4 v = { sp[0], sp[1], sp[2], sp[3] };
            __builtin_nontemporal_store(
                v, reinterpret_cast<vf4*>(orow + off[l] + base));
        }
    }
}

// ===================== fallback path (R5, proven) ==========================
__global__ void iir_prep_kernel(const float* __restrict__ As, int rows,
                                int* __restrict__ wrow, int* __restrict__ perm)
{
    __shared__ int sw[256];
    const int r = threadIdx.x;
    int W = 0;
    if (r < rows) {
        float r2max = 0.f;
#pragma unroll
        for (int k = 0; k < KB; ++k) {
            float a0 = As[(size_t)r * KB * 3 + 3 * k];
            float a2 = As[(size_t)r * KB * 3 + 3 * k + 2] / a0;
            r2max = fmaxf(r2max, a2);
        }
        float rmax = fminf(fmaxf(sqrtf(fmaxf(r2max, 0.f)), 0.20f), 0.955f);
        float Wf = 25.6f / (-logf(rmax));
        W = ((int)ceilf(Wf) + TT - 1) & ~(TT - 1);
        W = min(max(W, WMIN), WMAX);
        wrow[r] = W;
    }
    sw[r] = W;
    __syncthreads();
    if (r < rows) {
        int rank = 0;
        for (int i = 0; i < rows; ++i)
            rank += (sw[i] > W) || (sw[i] == W && i < r);
        perm[rank] = r;
    }
}

__global__ __launch_bounds__(TPB, 4) void iir_chunks_kernel(
    const float* __restrict__ x, const float* __restrict__ Bs,
    const float* __restrict__ As, float* __restrict__ out, int L,
    const int* __restrict__ wrow, const int* __restrict__ perm)
{
    __shared__ float lds[TPB * LSTR];
    const int tid = threadIdx.x;
    const int bpr = (L / SS) / TPB;
    const int row = perm[blockIdx.x / bpr];
    const int chunk0 = (blockIdx.x % bpr) * TPB;
    const int W = wrow[row];

    float b0[KB], b1[KB], b2[KB], na1[KB], na2[KB];
    const float* Bp = Bs + (size_t)row * KB * 3;
    const float* Ap = As + (size_t)row * KB * 3;
#pragma unroll
    for (int k = 0; k < KB; ++k) {
        float inv = 1.0f / Ap[3 * k];
        b0[k]  =  Bp[3 * k]     * inv;
        b1[k]  =  Bp[3 * k + 1] * inv;
        b2[k]  =  Bp[3 * k + 2] * inv;
        na1[k] = -Ap[3 * k + 1] * inv;
        na2[k] = -Ap[3 * k + 2] * inv;
    }

    float s1[KB] = {0.f, 0.f, 0.f, 0.f};
    float s2[KB] = {0.f, 0.f, 0.f, 0.f};

    const float* xrow = x   + (size_t)row * L;
    float*       orow = out + (size_t)row * L;
    float*       myrow = lds + tid * LSTR;

    const int tq = tid >> 3;
    const int p4 = (tid & 7) << 2;
    int off[NL], ldsoff[NL];
#pragma unroll
    for (int l = 0; l < NL; ++l) {
        int j = l * 32 + tq;
        off[l]    = (chunk0 + j) * SS + p4 - W;
        ldsoff[l] = j * LSTR + p4;
    }

    const int NT = (SS + W) / TT;
    const int WT = W / TT;

    float4 rn[NL];
#pragma unroll
    for (int l = 0; l < NL; ++l) {
        int pos = off[l];
        rn[l] = make_float4(0.f, 0.f, 0.f, 0.f);
        if (pos >= 0) rn[l] = *reinterpret_cast<const float4*>(xrow + pos);
    }

#pragma unroll 1
    for (int it = 0; it < NT; ++it) {
        __syncthreads();
#pragma unroll
        for (int l = 0; l < NL; ++l) {
            float* d = lds + ldsoff[l];
            d[0] = rn[l].x; d[1] = rn[l].y; d[2] = rn[l].z; d[3] = rn[l].w;
        }
        if (it + 1 < NT) {
            const int base = (it + 1) * TT;
#pragma unroll
            for (int l = 0; l < NL; ++l) {
                int pos = off[l] + base;
                rn[l] = make_float4(0.f, 0.f, 0.f, 0.f);
                if (pos >= 0) rn[l] = *reinterpret_cast<const float4*>(xrow + pos);
            }
        }
        __syncthreads();

        if (it < WT) {
#pragma unroll
            for (int p = 0; p < TT; ++p) {
                float u = myrow[p];
#pragma unroll
                for (int k = 0; k < KB; ++k) {
                    float yv = fmaf(b0[k], u, s1[k]);
                    s1[k] = fmaf(na1[k], yv, fmaf(b1[k], u, s2[k]));
                    s2[k] = fmaf(na2[k], yv, b2[k] * u);
                    u = yv;
                }
            }
        } else {
#pragma unroll
            for (int p = 0; p < TT; ++p) {
                float u = myrow[p];
#pragma unroll
                for (int k = 0; k < KB; ++k) {
                    float yv = fmaf(b0[k], u, s1[k]);
                    s1[k] = fmaf(na1[k], yv, fmaf(b1[k], u, s2[k]));
                    s2[k] = fmaf(na2[k], yv, b2[k] * u);
                    u = yv;
                }
                myrow[p] = u;
            }
            __syncthreads();

            const int base = it * TT - W;
#pragma unroll
            for (int l = 0; l < NL; ++l) {
                const float* sp = lds + ldsoff[l];
                vf4 v = { sp[0], sp[1], sp[2], sp[3] };
                __builtin_nontemporal_store(
                    v, reinterpret_cast<vf4*>(orow + off[l] + W + base));
            }
        }
    }
}

// ============================== launch =====================================
extern "C" void kernel_launch(void* const* d_in, const int* in_sizes, int n_in,
                              void* d_out, int out_size, void* d_ws, size_t ws_size,
                              hipStream_t stream) {
    const float* x  = (const float*)d_in[0];   // (B, C, L) f32
    const float* Bs = (const float*)d_in[1];   // (B, C, K, 3) f32
    const float* As = (const float*)d_in[2];   // (B, C, K, 3) f32
    float* out = (float*)d_out;                // (B, C, L) f32

    const int rows = in_sizes[1] / (KB * 3);   // B*C = 128
    const int L    = in_sizes[0] / rows;       // 131072
    const int cpr  = L / SS;                   // 2048 chunks per row
    const int bpr  = cpr / TPB;                // 8 blocks per row
    const int grid = rows * bpr;               // 1024

    // workspace layout
    float* dstate = (float*)d_ws;                              // rows*cpr*8
    float* nmatp  = dstate + (size_t)rows * cpr * 8;           // rows*320
    int*   nwrowp = (int*)(nmatp + (size_t)rows * 320);        // rows
    const size_t need = (size_t)((char*)(nwrowp + rows) - (char*)d_ws);

    if ((L % SS) == 0 && bpr * TPB == cpr && ws_size >= need) {
        hipLaunchKernelGGL(iir_state_kernel, dim3(grid), dim3(TPB), 0,
                           stream, x, Bs, As, L, dstate, nmatp, nwrowp);
        hipLaunchKernelGGL(iir_out_kernel, dim3(grid), dim3(TPB), 0,
                           stream, x, Bs, As, out, L, dstate, nmatp, nwrowp);
    } else {
        int* wrow = (int*)d_ws;
        int* perm = wrow + rows;
        hipLaunchKernelGGL(iir_prep_kernel, dim3(1), dim3(256), 0, stream,
                           As, rows, wrow, perm);
        hipLaunchKernelGGL(iir_chunks_kernel, dim3(rows * bpr), dim3(TPB), 0,
                           stream, x, Bs, As, out, L, wrow, perm);
    }
}